// Round 1
// baseline (1455.505 us; speedup 1.0000x reference)
//
#include <hip/hip_runtime.h>
#include <hip/hip_bf16.h>

#define N_NODES 100000
#define N_EDGES 3200000
#define NB      100
#define NPG     1000
#define DIN     128
#define DH      64
#define DE      32
#define NCLS    10
#define SCAN_BLOCKS 98   // ceil(100000/1024)

// ---------------- CSR build ----------------

__global__ void k_hist(const int* __restrict__ dst, int* __restrict__ cnt) {
    int i = blockIdx.x * 256 + threadIdx.x;
    if (i < N_EDGES) atomicAdd(&cnt[dst[i]], 1);
}

__global__ void k_dinv(const int* __restrict__ cnt, float* __restrict__ dinv) {
    int i = blockIdx.x * 256 + threadIdx.x;
    if (i < N_NODES) dinv[i] = rsqrtf((float)cnt[i] + 2.0f);
}

__global__ void k_scanA(const int* __restrict__ cnt, int* __restrict__ partials) {
    __shared__ int sm[256];
    int b = blockIdx.x, t = threadIdx.x;
    int base = b * 1024 + t * 4;
    int s = 0;
    for (int j = 0; j < 4; j++) {
        int idx = base + j;
        if (idx < N_NODES) s += cnt[idx];
    }
    sm[t] = s; __syncthreads();
    for (int off = 128; off > 0; off >>= 1) {
        if (t < off) sm[t] += sm[t + off];
        __syncthreads();
    }
    if (t == 0) partials[b] = sm[0];
}

__global__ void k_scanB(int* __restrict__ partials, int* __restrict__ rowptr) {
    if (threadIdx.x == 0 && blockIdx.x == 0) {
        int acc = 0;
        for (int i = 0; i < SCAN_BLOCKS; i++) {
            int v = partials[i]; partials[i] = acc; acc += v;
        }
        rowptr[N_NODES] = acc;  // == N_EDGES
    }
}

__global__ void k_scanC(const int* __restrict__ cnt, const int* __restrict__ partials,
                        int* __restrict__ rowptr) {
    __shared__ int sm[256];
    int b = blockIdx.x, t = threadIdx.x;
    int base = b * 1024 + t * 4;
    int v[4]; int s = 0;
    for (int j = 0; j < 4; j++) {
        int idx = base + j;
        v[j] = (idx < N_NODES) ? cnt[idx] : 0;
        s += v[j];
    }
    sm[t] = s; __syncthreads();
    for (int off = 1; off < 256; off <<= 1) {
        int x = 0;
        if (t >= off) x = sm[t - off];
        __syncthreads();
        sm[t] += x;
        __syncthreads();
    }
    int g = partials[b] + (sm[t] - s);   // exclusive prefix for this thread's chunk
    for (int j = 0; j < 4; j++) {
        int idx = base + j;
        if (idx < N_NODES) { rowptr[idx] = g; g += v[j]; }
    }
}

__global__ void k_scatter(const int* __restrict__ src, const int* __restrict__ dst,
                          const float* __restrict__ dinv, int* __restrict__ fill,
                          int* __restrict__ ssrc, float* __restrict__ scoef) {
    int i = blockIdx.x * 256 + threadIdx.x;
    if (i >= N_EDGES) return;
    int s = src[i], d = dst[i];
    int pos = atomicAdd(&fill[d], 1);
    ssrc[pos]  = s;
    scoef[pos] = dinv[s] * dinv[d];
}

// ---------------- GEMM 1: h = x @ [W_a1 | W_x1]  (128 -> 128) ----------------

__global__ __launch_bounds__(256) void k_gemm1(const float* __restrict__ x,
                                               const float* __restrict__ Wa,
                                               const float* __restrict__ Wx,
                                               float* __restrict__ h) {
    __shared__ float xs[32][128];
    __shared__ float ws[32][128];
    int t = threadIdx.x;
    int row0 = blockIdx.x * 32;
    // stage x tile [32][128]
    for (int i = 0; i < 4; i++) {
        int idx = t + 256 * i;           // float4 index 0..1023
        int r = idx >> 5, k4 = idx & 31;
        *(float4*)&xs[r][k4 * 4] = *(const float4*)&x[(size_t)(row0 + r) * 128 + k4 * 4];
    }
    float acc[4][4] = {};
    int rg = t >> 5, cg = t & 31;        // 8 row-groups x 32 col-groups (of 4)
    for (int kt = 0; kt < 4; kt++) {
        __syncthreads();
        // stage W tile rows kt*32..+32, all 128 concat cols
        for (int i = 0; i < 4; i++) {
            int idx = t + 256 * i;
            int kk = idx >> 5, c4 = idx & 31;
            int k = kt * 32 + kk, c = c4 * 4;
            float4 v;
            if (c < 64) v = *(const float4*)&Wa[k * 64 + c];
            else        v = *(const float4*)&Wx[k * 64 + (c - 64)];
            *(float4*)&ws[kk][c] = v;
        }
        __syncthreads();
        for (int kk = 0; kk < 32; kk++) {
            float4 w = *(float4*)&ws[kk][cg * 4];
            float xv[4];
            for (int i = 0; i < 4; i++) xv[i] = xs[rg * 4 + i][kt * 32 + kk];
            for (int i = 0; i < 4; i++) {
                acc[i][0] += xv[i] * w.x; acc[i][1] += xv[i] * w.y;
                acc[i][2] += xv[i] * w.z; acc[i][3] += xv[i] * w.w;
            }
        }
    }
    for (int i = 0; i < 4; i++) {
        int r = row0 + rg * 4 + i;
        *(float4*)&h[(size_t)r * 128 + cg * 4] =
            make_float4(acc[i][0], acc[i][1], acc[i][2], acc[i][3]);
    }
}

// ---------------- Aggregation, 128 channels (both branches, layer 1) ----------------
// out[n][c] = relu( sum_in coef*h[src][c] + 2*dinv^2*h[n][c] + bcat[c] )

__global__ __launch_bounds__(256) void k_agg128(const float* __restrict__ h,
                                                const int* __restrict__ rowptr,
                                                const int* __restrict__ ssrc,
                                                const float* __restrict__ scoef,
                                                const float* __restrict__ dinv,
                                                const float* __restrict__ ba,
                                                const float* __restrict__ bx,
                                                float* __restrict__ outB) {
    int wid  = blockIdx.x * 4 + (threadIdx.x >> 6);
    int lane = threadIdx.x & 63;
    if (wid >= N_NODES) return;
    const float2* h2 = (const float2*)h;
    float di = dinv[wid];
    float sw = 2.0f * di * di;
    float2 hv = h2[(size_t)wid * 64 + lane];
    float vx = sw * hv.x, vy = sw * hv.y;
    int e0 = rowptr[wid], e1 = rowptr[wid + 1];
    int e = e0;
    for (; e + 1 < e1; e += 2) {
        int s0 = ssrc[e], s1 = ssrc[e + 1];
        float c0 = scoef[e], c1 = scoef[e + 1];
        float2 p = h2[(size_t)s0 * 64 + lane];
        float2 q = h2[(size_t)s1 * 64 + lane];
        vx += c0 * p.x + c1 * q.x;
        vy += c0 * p.y + c1 * q.y;
    }
    if (e < e1) {
        int s0 = ssrc[e]; float c0 = scoef[e];
        float2 p = h2[(size_t)s0 * 64 + lane];
        vx += c0 * p.x; vy += c0 * p.y;
    }
    int c0i = 2 * lane;
    float b0 = (c0i < 64) ? ba[c0i] : bx[c0i - 64];
    float b1 = (c0i + 1 < 64) ? ba[c0i + 1] : bx[c0i + 1 - 64];
    vx = fmaxf(vx + b0, 0.0f);
    vy = fmaxf(vy + b1, 0.0f);
    ((float2*)outB)[(size_t)wid * 64 + lane] = make_float2(vx, vy);
}

// ---------------- GEMM 2: g2 = [a1|x1] @ blockdiag(W_a2, W_x2) (64ch out) ----------------

__global__ __launch_bounds__(256) void k_gemm2(const float* __restrict__ Bm,
                                               const float* __restrict__ Wa2,
                                               const float* __restrict__ Wx2,
                                               float* __restrict__ g2) {
    __shared__ float xs[64][132];   // padded: breaks 128-stride bank aliasing
    __shared__ float ws[64][68];
    int t = threadIdx.x;
    int row0 = blockIdx.x * 64;
    // stage weights: ws[k][c] = c<32 ? Wa2[k][c] : Wx2[k][c-32]
    for (int i = 0; i < 4; i++) {
        int idx = t + 256 * i;          // 1024 float4s
        int k = idx >> 4, c4 = idx & 15, c = c4 * 4;
        float4 v;
        if (c < 32) v = *(const float4*)&Wa2[k * 32 + c];
        else        v = *(const float4*)&Wx2[k * 32 + (c - 32)];
        *(float4*)&ws[k][c] = v;
    }
    // stage input tile [64][128]
    for (int i = 0; i < 8; i++) {
        int idx = t + 256 * i;          // 2048 float4s
        int r = idx >> 5, k4 = idx & 31;
        int rr = row0 + r; if (rr >= N_NODES) rr = N_NODES - 1;
        *(float4*)&xs[r][k4 * 4] = *(const float4*)&Bm[(size_t)rr * 128 + k4 * 4];
    }
    __syncthreads();
    int cg = t & 15, rg = t >> 4;       // 16 col-groups (of 4) x 16 row-groups (of 4)
    int koff = (cg < 8) ? 0 : 64;       // a-branch reads a1 (k 0..63), x-branch reads x1 (k 64..127)
    float acc[4][4] = {};
    for (int k = 0; k < 64; k++) {
        float4 w = *(float4*)&ws[k][cg * 4];
        float xv[4];
        for (int i = 0; i < 4; i++) xv[i] = xs[rg * 4 + i][koff + k];
        for (int i = 0; i < 4; i++) {
            acc[i][0] += xv[i] * w.x; acc[i][1] += xv[i] * w.y;
            acc[i][2] += xv[i] * w.z; acc[i][3] += xv[i] * w.w;
        }
    }
    for (int i = 0; i < 4; i++) {
        int r = row0 + rg * 4 + i;
        if (r < N_NODES)
            *(float4*)&g2[(size_t)r * 64 + cg * 4] =
                make_float4(acc[i][0], acc[i][1], acc[i][2], acc[i][3]);
    }
}

// ---------------- Aggregation, 64 channels (layer 2) ----------------
// c<32: a-branch pre-softmax (+b_a2, no relu); c>=32: x-branch (+b_x2, relu)

__global__ __launch_bounds__(256) void k_agg64(const float* __restrict__ g2,
                                               const int* __restrict__ rowptr,
                                               const int* __restrict__ ssrc,
                                               const float* __restrict__ scoef,
                                               const float* __restrict__ dinv,
                                               const float* __restrict__ ba2,
                                               const float* __restrict__ bx2,
                                               float* __restrict__ s2) {
    int wid  = blockIdx.x * 4 + (threadIdx.x >> 6);
    int lane = threadIdx.x & 63;
    if (wid >= N_NODES) return;
    float di = dinv[wid];
    float v = 2.0f * di * di * g2[(size_t)wid * 64 + lane];
    int e0 = rowptr[wid], e1 = rowptr[wid + 1];
    int e = e0;
    for (; e + 1 < e1; e += 2) {
        int s0 = ssrc[e], s1 = ssrc[e + 1];
        float c0 = scoef[e], c1 = scoef[e + 1];
        v += c0 * g2[(size_t)s0 * 64 + lane] + c1 * g2[(size_t)s1 * 64 + lane];
    }
    if (e < e1) v += scoef[e] * g2[(size_t)ssrc[e] * 64 + lane];
    if (lane < 32) {
        v += ba2[lane];
    } else {
        v = fmaxf(v + bx2[lane - 32], 0.0f);
    }
    s2[(size_t)wid * 64 + lane] = v;
}

// ---------------- Segment softmax over a-branch (cols 0..31), per graph ----------------
// writes unnormalized exp in place; 1/sum into sinv[B][32]

__global__ __launch_bounds__(256) void k_smax(float* __restrict__ s2, float* __restrict__ sinv) {
    __shared__ float red[8][32];
    int g = blockIdx.x, t = threadIdx.x;
    int c = t & 31, sub = t >> 5;
    size_t base = (size_t)g * NPG;
    float m = -1e30f;
    for (int n = sub; n < NPG; n += 8)
        m = fmaxf(m, s2[(base + n) * 64 + c]);
    red[sub][c] = m; __syncthreads();
    if (sub == 0) {
        for (int j = 1; j < 8; j++) m = fmaxf(m, red[j][c]);
        red[0][c] = m;
    }
    __syncthreads();
    m = red[0][c];
    __syncthreads();
    float sum = 0.0f;
    for (int n = sub; n < NPG; n += 8) {
        size_t idx = (base + n) * 64 + c;
        float e = expf(s2[idx] - m);
        s2[idx] = e;
        sum += e;
    }
    red[sub][c] = sum; __syncthreads();
    if (sub == 0) {
        for (int j = 1; j < 8; j++) sum += red[j][c];
        sinv[g * 32 + c] = 1.0f / sum;
    }
}

// ---------------- Bilinear pool + linear head + softmax, per graph ----------------

__global__ __launch_bounds__(256) void k_bmm(const float* __restrict__ s2,
                                             const float* __restrict__ sinv,
                                             const float* __restrict__ Wlin,
                                             const float* __restrict__ blin,
                                             float* __restrict__ out) {
    __shared__ float tile[64][64];
    __shared__ float part[NCLS];
    int g = blockIdx.x, t = threadIdx.x;
    int e = t & 31, fg = t >> 5;     // e: 0..31, fg: 8 groups of 4 f-cols
    float acc[4] = {};
    for (int n0 = 0; n0 < NPG; n0 += 64) {
        int cntn = NPG - n0; if (cntn > 64) cntn = 64;
        __syncthreads();
        for (int i = 0; i < 4; i++) {
            int idx = t + 256 * i;         // 1024 float4s
            int r = idx >> 4, c4 = idx & 15;
            if (r < cntn)
                *(float4*)&tile[r][c4 * 4] =
                    *(const float4*)&s2[((size_t)g * NPG + n0 + r) * 64 + c4 * 4];
        }
        __syncthreads();
        for (int n = 0; n < cntn; n++) {
            float a  = tile[n][e];
            float4 xv = *(float4*)&tile[n][32 + fg * 4];
            acc[0] += a * xv.x; acc[1] += a * xv.y;
            acc[2] += a * xv.z; acc[3] += a * xv.w;
        }
    }
    float si = sinv[g * 32 + e];
    float p[NCLS];
    for (int c = 0; c < NCLS; c++) p[c] = 0.0f;
    int kbase = e * 32 + fg * 4;
    for (int j = 0; j < 4; j++) {
        float a = acc[j] * si;
        const float* wrow = &Wlin[(size_t)(kbase + j) * NCLS];
        for (int c = 0; c < NCLS; c++) p[c] += a * wrow[c];
    }
    if (t < NCLS) part[t] = 0.0f;
    __syncthreads();
    for (int c = 0; c < NCLS; c++) atomicAdd(&part[c], p[c]);
    __syncthreads();
    if (t == 0) {
        float logits[NCLS]; float mx = -1e30f;
        for (int c = 0; c < NCLS; c++) { logits[c] = part[c] + blin[c]; mx = fmaxf(mx, logits[c]); }
        float s = 0.0f;
        for (int c = 0; c < NCLS; c++) { logits[c] = expf(logits[c] - mx); s += logits[c]; }
        float inv = 1.0f / s;
        for (int c = 0; c < NCLS; c++) out[g * NCLS + c] = logits[c] * inv;
    }
}

// ---------------- launch ----------------

extern "C" void kernel_launch(void* const* d_in, const int* in_sizes, int n_in,
                              void* d_out, int out_size, void* d_ws, size_t ws_size,
                              hipStream_t stream) {
    const float* x    = (const float*)d_in[0];
    const int*   ei   = (const int*)d_in[1];
    // d_in[2] = batch (unused: graphs are uniform NPG blocks)
    const float* Wa1  = (const float*)d_in[3];
    const float* ba1  = (const float*)d_in[4];
    const float* Wa2  = (const float*)d_in[5];
    const float* ba2  = (const float*)d_in[6];
    const float* Wx1  = (const float*)d_in[7];
    const float* bx1  = (const float*)d_in[8];
    const float* Wx2  = (const float*)d_in[9];
    const float* bx2  = (const float*)d_in[10];
    const float* Wlin = (const float*)d_in[11];
    const float* blin = (const float*)d_in[12];
    float* out = (float*)d_out;

    char* w = (char*)d_ws;
    auto alloc = [&](size_t bytes) -> void* {
        void* p = (void*)w;
        w += (bytes + 255) & ~(size_t)255;
        return p;
    };
    int*   cnt      = (int*)alloc((N_NODES + 1) * sizeof(int));
    int*   rowptr   = (int*)alloc((N_NODES + 1) * sizeof(int));
    int*   fill     = (int*)alloc(N_NODES * sizeof(int));
    float* dinv     = (float*)alloc(N_NODES * sizeof(float));
    int*   partials = (int*)alloc(1024);
    int*   ssrc     = (int*)alloc((size_t)N_EDGES * sizeof(int));
    float* scoef    = (float*)alloc((size_t)N_EDGES * sizeof(float));
    float* sinv     = (float*)alloc(NB * DE * sizeof(float));
    float* bufA     = (float*)alloc((size_t)N_NODES * 128 * sizeof(float));
    float* bufB     = (float*)alloc((size_t)N_NODES * 128 * sizeof(float));

    const int* srcp = ei;
    const int* dstp = ei + N_EDGES;

    hipMemsetAsync(cnt, 0, (N_NODES + 1) * sizeof(int), stream);
    k_hist<<<(N_EDGES + 255) / 256, 256, 0, stream>>>(dstp, cnt);
    k_dinv<<<(N_NODES + 255) / 256, 256, 0, stream>>>(cnt, dinv);
    k_scanA<<<SCAN_BLOCKS, 256, 0, stream>>>(cnt, partials);
    k_scanB<<<1, 64, 0, stream>>>(partials, rowptr);
    k_scanC<<<SCAN_BLOCKS, 256, 0, stream>>>(cnt, partials, rowptr);
    hipMemcpyAsync(fill, rowptr, N_NODES * sizeof(int), hipMemcpyDeviceToDevice, stream);
    k_scatter<<<(N_EDGES + 255) / 256, 256, 0, stream>>>(srcp, dstp, dinv, fill, ssrc, scoef);

    k_gemm1<<<N_NODES / 32, 256, 0, stream>>>(x, Wa1, Wx1, bufA);
    k_agg128<<<N_NODES / 4, 256, 0, stream>>>(bufA, rowptr, ssrc, scoef, dinv, ba1, bx1, bufB);
    k_gemm2<<<(N_NODES + 63) / 64, 256, 0, stream>>>(bufB, Wa2, Wx2, bufA);
    k_agg64<<<N_NODES / 4, 256, 0, stream>>>(bufA, rowptr, ssrc, scoef, dinv, ba2, bx2, bufB);
    k_smax<<<NB, 256, 0, stream>>>(bufB, sinv);
    k_bmm<<<NB, 256, 0, stream>>>(bufB, sinv, Wlin, blin, out);
}

// Round 2
// 913.621 us; speedup vs baseline: 1.5931x; 1.5931x over previous
//
#include <hip/hip_runtime.h>
#include <hip/hip_bf16.h>

#define N_NODES 100000
#define N_EDGES 3200000
#define NB      100
#define NPG     1000
#define DIN     128
#define DH      64
#define DE      32
#define NCLS    10
#define SCAN_BLOCKS 98   // ceil(100000/1024)
#define POOL_CHUNK 250   // nodes per k_pool block (4 chunks/graph)

// ---------------- CSR build ----------------

__global__ void k_hist(const int* __restrict__ dst, int* __restrict__ cnt) {
    int i = blockIdx.x * 256 + threadIdx.x;
    if (i < N_EDGES) atomicAdd(&cnt[dst[i]], 1);
}

__global__ void k_dinv(const int* __restrict__ cnt, float* __restrict__ dinv) {
    int i = blockIdx.x * 256 + threadIdx.x;
    if (i < N_NODES) dinv[i] = rsqrtf((float)cnt[i] + 2.0f);
}

__global__ void k_scanA(const int* __restrict__ cnt, int* __restrict__ partials) {
    __shared__ int sm[256];
    int b = blockIdx.x, t = threadIdx.x;
    int base = b * 1024 + t * 4;
    int s = 0;
    for (int j = 0; j < 4; j++) {
        int idx = base + j;
        if (idx < N_NODES) s += cnt[idx];
    }
    sm[t] = s; __syncthreads();
    for (int off = 128; off > 0; off >>= 1) {
        if (t < off) sm[t] += sm[t + off];
        __syncthreads();
    }
    if (t == 0) partials[b] = sm[0];
}

__global__ void k_scanB(int* __restrict__ partials, int* __restrict__ rowptr) {
    if (threadIdx.x == 0 && blockIdx.x == 0) {
        int acc = 0;
        for (int i = 0; i < SCAN_BLOCKS; i++) {
            int v = partials[i]; partials[i] = acc; acc += v;
        }
        rowptr[N_NODES] = acc;  // == N_EDGES
    }
}

__global__ void k_scanC(const int* __restrict__ cnt, const int* __restrict__ partials,
                        int* __restrict__ rowptr) {
    __shared__ int sm[256];
    int b = blockIdx.x, t = threadIdx.x;
    int base = b * 1024 + t * 4;
    int v[4]; int s = 0;
    for (int j = 0; j < 4; j++) {
        int idx = base + j;
        v[j] = (idx < N_NODES) ? cnt[idx] : 0;
        s += v[j];
    }
    sm[t] = s; __syncthreads();
    for (int off = 1; off < 256; off <<= 1) {
        int x = 0;
        if (t >= off) x = sm[t - off];
        __syncthreads();
        sm[t] += x;
        __syncthreads();
    }
    int g = partials[b] + (sm[t] - s);   // exclusive prefix for this thread's chunk
    for (int j = 0; j < 4; j++) {
        int idx = base + j;
        if (idx < N_NODES) { rowptr[idx] = g; g += v[j]; }
    }
}

__global__ void k_scatter(const int* __restrict__ src, const int* __restrict__ dst,
                          const float* __restrict__ dinv, int* __restrict__ fill,
                          int* __restrict__ ssrc, float* __restrict__ scoef) {
    int i = blockIdx.x * 256 + threadIdx.x;
    if (i >= N_EDGES) return;
    int s = src[i], d = dst[i];
    int pos = atomicAdd(&fill[d], 1);
    ssrc[pos]  = s;
    scoef[pos] = dinv[s] * dinv[d];
}

// ---------------- GEMM 1: h = x @ [W_a1 | W_x1]  (128 -> 128) ----------------

__global__ __launch_bounds__(256) void k_gemm1(const float* __restrict__ x,
                                               const float* __restrict__ Wa,
                                               const float* __restrict__ Wx,
                                               float* __restrict__ h) {
    __shared__ float xs[32][128];
    __shared__ float ws[32][128];
    int t = threadIdx.x;
    int row0 = blockIdx.x * 32;
    // stage x tile [32][128]
    for (int i = 0; i < 4; i++) {
        int idx = t + 256 * i;           // float4 index 0..1023
        int r = idx >> 5, k4 = idx & 31;
        *(float4*)&xs[r][k4 * 4] = *(const float4*)&x[(size_t)(row0 + r) * 128 + k4 * 4];
    }
    float acc[4][4] = {};
    int rg = t >> 5, cg = t & 31;        // 8 row-groups x 32 col-groups (of 4)
    for (int kt = 0; kt < 4; kt++) {
        __syncthreads();
        // stage W tile rows kt*32..+32, all 128 concat cols
        for (int i = 0; i < 4; i++) {
            int idx = t + 256 * i;
            int kk = idx >> 5, c4 = idx & 31;
            int k = kt * 32 + kk, c = c4 * 4;
            float4 v;
            if (c < 64) v = *(const float4*)&Wa[k * 64 + c];
            else        v = *(const float4*)&Wx[k * 64 + (c - 64)];
            *(float4*)&ws[kk][c] = v;
        }
        __syncthreads();
        for (int kk = 0; kk < 32; kk++) {
            float4 w = *(float4*)&ws[kk][cg * 4];
            float xv[4];
            for (int i = 0; i < 4; i++) xv[i] = xs[rg * 4 + i][kt * 32 + kk];
            for (int i = 0; i < 4; i++) {
                acc[i][0] += xv[i] * w.x; acc[i][1] += xv[i] * w.y;
                acc[i][2] += xv[i] * w.z; acc[i][3] += xv[i] * w.w;
            }
        }
    }
    for (int i = 0; i < 4; i++) {
        int r = row0 + rg * 4 + i;
        *(float4*)&h[(size_t)r * 128 + cg * 4] =
            make_float4(acc[i][0], acc[i][1], acc[i][2], acc[i][3]);
    }
}

// ---------------- Aggregation, 128 channels (both branches, layer 1) ----------------
// out[n][c] = relu( sum_in coef*h[src][c] + 2*dinv^2*h[n][c] + bcat[c] )

__global__ __launch_bounds__(256) void k_agg128(const float* __restrict__ h,
                                                const int* __restrict__ rowptr,
                                                const int* __restrict__ ssrc,
                                                const float* __restrict__ scoef,
                                                const float* __restrict__ dinv,
                                                const float* __restrict__ ba,
                                                const float* __restrict__ bx,
                                                float* __restrict__ outB) {
    int wid  = blockIdx.x * 4 + (threadIdx.x >> 6);
    int lane = threadIdx.x & 63;
    if (wid >= N_NODES) return;
    const float2* h2 = (const float2*)h;
    float di = dinv[wid];
    float sw = 2.0f * di * di;
    float2 hv = h2[(size_t)wid * 64 + lane];
    float vx = sw * hv.x, vy = sw * hv.y;
    int e0 = rowptr[wid], e1 = rowptr[wid + 1];
    int e = e0;
    for (; e + 1 < e1; e += 2) {
        int s0 = ssrc[e], s1 = ssrc[e + 1];
        float c0 = scoef[e], c1 = scoef[e + 1];
        float2 p = h2[(size_t)s0 * 64 + lane];
        float2 q = h2[(size_t)s1 * 64 + lane];
        vx += c0 * p.x + c1 * q.x;
        vy += c0 * p.y + c1 * q.y;
    }
    if (e < e1) {
        int s0 = ssrc[e]; float c0 = scoef[e];
        float2 p = h2[(size_t)s0 * 64 + lane];
        vx += c0 * p.x; vy += c0 * p.y;
    }
    int c0i = 2 * lane;
    float b0 = (c0i < 64) ? ba[c0i] : bx[c0i - 64];
    float b1 = (c0i + 1 < 64) ? ba[c0i + 1] : bx[c0i + 1 - 64];
    vx = fmaxf(vx + b0, 0.0f);
    vy = fmaxf(vy + b1, 0.0f);
    ((float2*)outB)[(size_t)wid * 64 + lane] = make_float2(vx, vy);
}

// ---------------- GEMM 2: g2 = [a1|x1] @ blockdiag(W_a2, W_x2) (64ch out) ----------------

__global__ __launch_bounds__(256) void k_gemm2(const float* __restrict__ Bm,
                                               const float* __restrict__ Wa2,
                                               const float* __restrict__ Wx2,
                                               float* __restrict__ g2) {
    __shared__ float xs[64][132];   // padded: breaks 128-stride bank aliasing
    __shared__ float ws[64][68];
    int t = threadIdx.x;
    int row0 = blockIdx.x * 64;
    // stage weights: ws[k][c] = c<32 ? Wa2[k][c] : Wx2[k][c-32]
    for (int i = 0; i < 4; i++) {
        int idx = t + 256 * i;          // 1024 float4s
        int k = idx >> 4, c4 = idx & 15, c = c4 * 4;
        float4 v;
        if (c < 32) v = *(const float4*)&Wa2[k * 32 + c];
        else        v = *(const float4*)&Wx2[k * 32 + (c - 32)];
        *(float4*)&ws[k][c] = v;
    }
    // stage input tile [64][128]
    for (int i = 0; i < 8; i++) {
        int idx = t + 256 * i;          // 2048 float4s
        int r = idx >> 5, k4 = idx & 31;
        int rr = row0 + r; if (rr >= N_NODES) rr = N_NODES - 1;
        *(float4*)&xs[r][k4 * 4] = *(const float4*)&Bm[(size_t)rr * 128 + k4 * 4];
    }
    __syncthreads();
    int cg = t & 15, rg = t >> 4;       // 16 col-groups (of 4) x 16 row-groups (of 4)
    int koff = (cg < 8) ? 0 : 64;       // a-branch reads a1 (k 0..63), x-branch reads x1 (k 64..127)
    float acc[4][4] = {};
    for (int k = 0; k < 64; k++) {
        float4 w = *(float4*)&ws[k][cg * 4];
        float xv[4];
        for (int i = 0; i < 4; i++) xv[i] = xs[rg * 4 + i][koff + k];
        for (int i = 0; i < 4; i++) {
            acc[i][0] += xv[i] * w.x; acc[i][1] += xv[i] * w.y;
            acc[i][2] += xv[i] * w.z; acc[i][3] += xv[i] * w.w;
        }
    }
    for (int i = 0; i < 4; i++) {
        int r = row0 + rg * 4 + i;
        if (r < N_NODES)
            *(float4*)&g2[(size_t)r * 64 + cg * 4] =
                make_float4(acc[i][0], acc[i][1], acc[i][2], acc[i][3]);
    }
}

// ---------------- Aggregation, 64 channels (layer 2) ----------------
// c<32: a-branch pre-softmax (+b_a2, no relu); c>=32: x-branch (+b_x2, relu)

__global__ __launch_bounds__(256) void k_agg64(const float* __restrict__ g2,
                                               const int* __restrict__ rowptr,
                                               const int* __restrict__ ssrc,
                                               const float* __restrict__ scoef,
                                               const float* __restrict__ dinv,
                                               const float* __restrict__ ba2,
                                               const float* __restrict__ bx2,
                                               float* __restrict__ s2) {
    int wid  = blockIdx.x * 4 + (threadIdx.x >> 6);
    int lane = threadIdx.x & 63;
    if (wid >= N_NODES) return;
    float di = dinv[wid];
    float v = 2.0f * di * di * g2[(size_t)wid * 64 + lane];
    int e0 = rowptr[wid], e1 = rowptr[wid + 1];
    int e = e0;
    for (; e + 1 < e1; e += 2) {
        int s0 = ssrc[e], s1 = ssrc[e + 1];
        float c0 = scoef[e], c1 = scoef[e + 1];
        v += c0 * g2[(size_t)s0 * 64 + lane] + c1 * g2[(size_t)s1 * 64 + lane];
    }
    if (e < e1) v += scoef[e] * g2[(size_t)ssrc[e] * 64 + lane];
    if (lane < 32) {
        v += ba2[lane];
    } else {
        v = fmaxf(v + bx2[lane - 32], 0.0f);
    }
    s2[(size_t)wid * 64 + lane] = v;
}

// ---------------- Segment softmax over a-branch (cols 0..31), per graph ----------------
// writes unnormalized exp in place; 1/sum into sinv[B][32]

__global__ __launch_bounds__(256) void k_smax(float* __restrict__ s2, float* __restrict__ sinv) {
    __shared__ float red[8][32];
    int g = blockIdx.x, t = threadIdx.x;
    int c = t & 31, sub = t >> 5;
    size_t base = (size_t)g * NPG;
    float m = -1e30f;
    for (int n = sub; n < NPG; n += 8)
        m = fmaxf(m, s2[(base + n) * 64 + c]);
    red[sub][c] = m; __syncthreads();
    if (sub == 0) {
        for (int j = 1; j < 8; j++) m = fmaxf(m, red[j][c]);
        red[0][c] = m;
    }
    __syncthreads();
    m = red[0][c];
    __syncthreads();
    float sum = 0.0f;
    for (int n = sub; n < NPG; n += 8) {
        size_t idx = (base + n) * 64 + c;
        float e = expf(s2[idx] - m);
        s2[idx] = e;
        sum += e;
    }
    red[sub][c] = sum; __syncthreads();
    if (sub == 0) {
        for (int j = 1; j < 8; j++) sum += red[j][c];
        sinv[g * 32 + c] = 1.0f / sum;
    }
}

// ---------------- Bilinear pool: prods[g][e][f] += sum_n ea[n,e]*x2[n,f] ----------------
// grid = NB*4 (4 node-chunks per graph); sinv folded in later by k_head.

__global__ __launch_bounds__(256) void k_pool(const float* __restrict__ s2,
                                              float* __restrict__ prods) {
    __shared__ float tile[64][64];
    int g  = blockIdx.x >> 2;
    int ch = blockIdx.x & 3;
    int t  = threadIdx.x;
    int e  = t >> 3;            // 0..31
    int f4 = t & 7;             // group of 4 f-cols
    float a0 = 0.f, a1 = 0.f, a2 = 0.f, a3 = 0.f;
    int base = g * NPG + ch * POOL_CHUNK;
    for (int n0 = 0; n0 < POOL_CHUNK; n0 += 64) {
        int cnt = POOL_CHUNK - n0; if (cnt > 64) cnt = 64;
        __syncthreads();
        for (int i = t; i < cnt * 16; i += 256) {
            int r = i >> 4, c4 = i & 15;
            *(float4*)&tile[r][c4 * 4] =
                *(const float4*)&s2[(size_t)(base + n0 + r) * 64 + c4 * 4];
        }
        __syncthreads();
        for (int n = 0; n < cnt; n++) {
            float a   = tile[n][e];
            float4 xv = *(float4*)&tile[n][32 + f4 * 4];
            a0 += a * xv.x; a1 += a * xv.y; a2 += a * xv.z; a3 += a * xv.w;
        }
    }
    float* dp = &prods[(size_t)g * 1024 + e * 32 + f4 * 4];
    atomicAdd(dp + 0, a0); atomicAdd(dp + 1, a1);
    atomicAdd(dp + 2, a2); atomicAdd(dp + 3, a3);
}

// ---------------- Head: out[g] = softmax( (sinv⊙prods) @ Wlin + blin ) ----------------

__global__ __launch_bounds__(256) void k_head(const float* __restrict__ prods,
                                              const float* __restrict__ sinv,
                                              const float* __restrict__ Wlin,
                                              const float* __restrict__ blin,
                                              float* __restrict__ out) {
    __shared__ float red[4][NCLS];
    int g = blockIdx.x, t = threadIdx.x;
    float p[NCLS];
    for (int c = 0; c < NCLS; c++) p[c] = 0.0f;
    for (int j = 0; j < 4; j++) {
        int k = t * 4 + j;              // k = e*32 + f, 0..1023
        int e = k >> 5;
        float v = prods[(size_t)g * 1024 + k] * sinv[g * 32 + e];
        const float* wrow = &Wlin[(size_t)k * NCLS];
        for (int c = 0; c < NCLS; c++) p[c] += v * wrow[c];
    }
    for (int off = 32; off > 0; off >>= 1)
        for (int c = 0; c < NCLS; c++) p[c] += __shfl_down(p[c], off, 64);
    int wave = t >> 6, lane = t & 63;
    if (lane == 0)
        for (int c = 0; c < NCLS; c++) red[wave][c] = p[c];
    __syncthreads();
    if (t == 0) {
        float logits[NCLS]; float mx = -1e30f;
        for (int c = 0; c < NCLS; c++) {
            logits[c] = red[0][c] + red[1][c] + red[2][c] + red[3][c] + blin[c];
            mx = fmaxf(mx, logits[c]);
        }
        float s = 0.0f;
        for (int c = 0; c < NCLS; c++) { logits[c] = expf(logits[c] - mx); s += logits[c]; }
        float inv = 1.0f / s;
        for (int c = 0; c < NCLS; c++) out[g * NCLS + c] = logits[c] * inv;
    }
}

// ---------------- launch ----------------

extern "C" void kernel_launch(void* const* d_in, const int* in_sizes, int n_in,
                              void* d_out, int out_size, void* d_ws, size_t ws_size,
                              hipStream_t stream) {
    const float* x    = (const float*)d_in[0];
    const int*   ei   = (const int*)d_in[1];
    // d_in[2] = batch (unused: graphs are uniform NPG blocks)
    const float* Wa1  = (const float*)d_in[3];
    const float* ba1  = (const float*)d_in[4];
    const float* Wa2  = (const float*)d_in[5];
    const float* ba2  = (const float*)d_in[6];
    const float* Wx1  = (const float*)d_in[7];
    const float* bx1  = (const float*)d_in[8];
    const float* Wx2  = (const float*)d_in[9];
    const float* bx2  = (const float*)d_in[10];
    const float* Wlin = (const float*)d_in[11];
    const float* blin = (const float*)d_in[12];
    float* out = (float*)d_out;

    char* w = (char*)d_ws;
    auto alloc = [&](size_t bytes) -> void* {
        void* p = (void*)w;
        w += (bytes + 255) & ~(size_t)255;
        return p;
    };
    int*   cnt      = (int*)alloc((N_NODES + 1) * sizeof(int));
    int*   rowptr   = (int*)alloc((N_NODES + 1) * sizeof(int));
    int*   fill     = (int*)alloc(N_NODES * sizeof(int));
    float* dinv     = (float*)alloc(N_NODES * sizeof(float));
    int*   partials = (int*)alloc(1024);
    int*   ssrc     = (int*)alloc((size_t)N_EDGES * sizeof(int));
    float* scoef    = (float*)alloc((size_t)N_EDGES * sizeof(float));
    float* sinv     = (float*)alloc(NB * DE * sizeof(float));
    float* prods    = (float*)alloc((size_t)NB * DE * DE * sizeof(float));
    float* bufA     = (float*)alloc((size_t)N_NODES * 128 * sizeof(float));
    float* bufB     = (float*)alloc((size_t)N_NODES * 128 * sizeof(float));

    const int* srcp = ei;
    const int* dstp = ei + N_EDGES;

    hipMemsetAsync(cnt, 0, (N_NODES + 1) * sizeof(int), stream);
    hipMemsetAsync(prods, 0, (size_t)NB * DE * DE * sizeof(float), stream);
    k_hist<<<(N_EDGES + 255) / 256, 256, 0, stream>>>(dstp, cnt);
    k_dinv<<<(N_NODES + 255) / 256, 256, 0, stream>>>(cnt, dinv);
    k_scanA<<<SCAN_BLOCKS, 256, 0, stream>>>(cnt, partials);
    k_scanB<<<1, 64, 0, stream>>>(partials, rowptr);
    k_scanC<<<SCAN_BLOCKS, 256, 0, stream>>>(cnt, partials, rowptr);
    hipMemcpyAsync(fill, rowptr, N_NODES * sizeof(int), hipMemcpyDeviceToDevice, stream);
    k_scatter<<<(N_EDGES + 255) / 256, 256, 0, stream>>>(srcp, dstp, dinv, fill, ssrc, scoef);

    k_gemm1<<<N_NODES / 32, 256, 0, stream>>>(x, Wa1, Wx1, bufA);
    k_agg128<<<N_NODES / 4, 256, 0, stream>>>(bufA, rowptr, ssrc, scoef, dinv, ba1, bx1, bufB);
    k_gemm2<<<(N_NODES + 63) / 64, 256, 0, stream>>>(bufB, Wa2, Wx2, bufA);
    k_agg64<<<N_NODES / 4, 256, 0, stream>>>(bufA, rowptr, ssrc, scoef, dinv, ba2, bx2, bufB);
    k_smax<<<NB, 256, 0, stream>>>(bufB, sinv);
    k_pool<<<NB * 4, 256, 0, stream>>>(bufB, prods);
    k_head<<<NB, 256, 0, stream>>>(prods, sinv, Wlin, blin, out);
}